// Round 1
// baseline (2885.065 us; speedup 1.0000x reference)
//
#include <hip/hip_runtime.h>

#define CH 128
#define NCLS 16

// ---------------------------------------------------------------- degree
__global__ void zero_kernel(float* __restrict__ p, int n) {
    int i = blockIdx.x * blockDim.x + threadIdx.x;
    if (i < n) p[i] = 0.0f;
}

__global__ void count_deg_kernel(const int* __restrict__ dst,
                                 float* __restrict__ deg, int E) {
    int e = blockIdx.x * blockDim.x + threadIdx.x;
    if (e < E) atomicAdd(&deg[dst[e]], 1.0f);
}

__global__ void dis_kernel(const float* __restrict__ deg,
                           float* __restrict__ dis, int n) {
    int i = blockIdx.x * blockDim.x + threadIdx.x;
    if (i < n) dis[i] = rsqrtf(deg[i] + 1.0f);   // +1 = self-loop
}

// ---------------------------------------------------------------- GEMM 128x128
// C[n_rows x 128] = relu?(A[n_rows x 128]) @ W[128 x 128]
// block = 256 threads, BM=64 rows/block, BK=32, each thread: 8 rows x 4 cols.
template <bool RELU_IN>
__global__ __launch_bounds__(256) void gemm_128_128(
    const float* __restrict__ A, const float* __restrict__ W,
    float* __restrict__ C, int n_rows) {
    __shared__ float As[64][33];    // +1 pad breaks stride-32 conflicts
    __shared__ float Ws[32][132];   // row stride 132*4=528B, 16B-aligned for float4

    const int tid = threadIdx.x;
    const int bm0 = blockIdx.x * 64;
    const int tc = tid & 31;   // col group: cols tc*4 .. tc*4+3
    const int tr = tid >> 5;   // row group: rows tr*8 .. tr*8+7

    float acc[8][4];
#pragma unroll
    for (int i = 0; i < 8; i++)
#pragma unroll
        for (int j = 0; j < 4; j++) acc[i][j] = 0.0f;

    for (int k0 = 0; k0 < 128; k0 += 32) {
        // A tile: 64x32 = 2048 elems, 8 per thread, coalesced
#pragma unroll
        for (int i = 0; i < 8; i++) {
            int l = tid + i * 256;
            int r = l >> 5, c = l & 31;
            int gr = bm0 + r;
            float v = (gr < n_rows) ? A[(size_t)gr * CH + k0 + c] : 0.0f;
            if (RELU_IN) v = fmaxf(v, 0.0f);
            As[r][c] = v;
        }
        // W tile: 32x128 = 4096 elems, 16 per thread, coalesced
#pragma unroll
        for (int i = 0; i < 16; i++) {
            int l = tid + i * 256;
            int r = l >> 7, c = l & 127;
            Ws[r][c] = W[(k0 + r) * CH + c];
        }
        __syncthreads();
#pragma unroll
        for (int kk = 0; kk < 32; kk++) {
            float4 b = *(const float4*)&Ws[kk][tc * 4];
            float a[8];
#pragma unroll
            for (int i = 0; i < 8; i++) a[i] = As[tr * 8 + i][kk];
#pragma unroll
            for (int i = 0; i < 8; i++) {
                acc[i][0] = fmaf(a[i], b.x, acc[i][0]);
                acc[i][1] = fmaf(a[i], b.y, acc[i][1]);
                acc[i][2] = fmaf(a[i], b.z, acc[i][2]);
                acc[i][3] = fmaf(a[i], b.w, acc[i][3]);
            }
        }
        __syncthreads();
    }
#pragma unroll
    for (int i = 0; i < 8; i++) {
        int gr = bm0 + tr * 8 + i;
        if (gr < n_rows) {
            float4 v = make_float4(acc[i][0], acc[i][1], acc[i][2], acc[i][3]);
            *(float4*)&C[(size_t)gr * CH + tc * 4] = v;
        }
    }
}

// ---------------------------------------------------------------- scatter init
// out[i,c] = bias[c] + dis[i]^2 * h[i,c]   (bias + self-loop message)
__global__ void init_out_kernel(const float* __restrict__ h,
                                const float* __restrict__ dis,
                                const float* __restrict__ bias,
                                float* __restrict__ out, int n) {
    int t = blockIdx.x * blockDim.x + threadIdx.x;
    int i = t >> 5, c4 = t & 31;
    if (i >= n) return;
    float d = dis[i];
    float s = d * d;
    float4 hv = *(const float4*)&h[(size_t)i * CH + c4 * 4];
    float4 bv = *(const float4*)&bias[c4 * 4];
    float4 o = make_float4(bv.x + s * hv.x, bv.y + s * hv.y,
                           bv.z + s * hv.z, bv.w + s * hv.w);
    *(float4*)&out[(size_t)i * CH + c4 * 4] = o;
}

// ---------------------------------------------------------------- edge scatter
// out[dst,c] += dis[src]*dis[dst] * h[src,c]; 32 threads (c4 groups) per edge
__global__ void edge_scatter_kernel(const int* __restrict__ src,
                                    const int* __restrict__ dst,
                                    const float* __restrict__ dis,
                                    const float* __restrict__ h,
                                    float* __restrict__ out, int E) {
    int t = blockIdx.x * blockDim.x + threadIdx.x;
    int e = t >> 5, c4 = t & 31;
    if (e >= E) return;
    int s = src[e], d = dst[e];
    float norm = dis[s] * dis[d];
    float4 hv = *(const float4*)&h[(size_t)s * CH + c4 * 4];
    float* o = &out[(size_t)d * CH + c4 * 4];
    atomicAdd(o + 0, norm * hv.x);
    atomicAdd(o + 1, norm * hv.y);
    atomicAdd(o + 2, norm * hv.z);
    atomicAdd(o + 3, norm * hv.w);
}

// ---------------------------------------------------------------- head
// out[n x 16] = relu(A[n x 128]) @ Wh[128 x 16] + bh
__global__ __launch_bounds__(256) void head_kernel(
    const float* __restrict__ A, const float* __restrict__ Wh,
    const float* __restrict__ bh, float* __restrict__ out, int n) {
    __shared__ float Ws[CH * NCLS];  // [k][c] layout, 8 KB
    __shared__ float As[16][129];
    const int tid = threadIdx.x;
    const int n0 = blockIdx.x * 16;
#pragma unroll
    for (int i = 0; i < 8; i++) {
        int l = tid + i * 256;
        Ws[l] = Wh[l];
    }
#pragma unroll
    for (int i = 0; i < 8; i++) {
        int l = tid + i * 256;
        int r = l >> 7, c = l & 127;
        int gr = n0 + r;
        As[r][c] = (gr < n) ? fmaxf(A[(size_t)gr * CH + c], 0.0f) : 0.0f;
    }
    __syncthreads();
    int r = tid >> 4, c = tid & 15;
    float acc = bh[c];
#pragma unroll
    for (int k = 0; k < CH; k++) acc = fmaf(As[r][k], Ws[k * NCLS + c], acc);
    int gr = n0 + r;
    if (gr < n) out[(size_t)gr * NCLS + c] = acc;
}

// ---------------------------------------------------------------- launch
extern "C" void kernel_launch(void* const* d_in, const int* in_sizes, int n_in,
                              void* d_out, int out_size, void* d_ws, size_t ws_size,
                              hipStream_t stream) {
    const float* x  = (const float*)d_in[0];
    const int*   ei = (const int*)d_in[1];
    const float* W1 = (const float*)d_in[2];
    const float* b1 = (const float*)d_in[3];
    const float* W2 = (const float*)d_in[4];
    const float* b2 = (const float*)d_in[5];
    const float* Wh = (const float*)d_in[6];
    const float* bh = (const float*)d_in[7];
    float* out = (float*)d_out;

    const int n = in_sizes[0] / CH;   // 50000
    const int E = in_sizes[1] / 2;    // 800000
    const int* src = ei;
    const int* dst = ei + E;

    float* ws   = (float*)d_ws;
    float* deg  = ws;                       // n
    float* dis  = ws + n;                   // n
    float* bufA = ws + 2 * (size_t)n;       // n*128  (2n floats = 400000B, 16B-aligned)
    float* bufB = bufA + (size_t)n * CH;    // n*128

    const int B = 256;
    // degree + normalization
    zero_kernel<<<(n + B - 1) / B, B, 0, stream>>>(deg, n);
    count_deg_kernel<<<(E + B - 1) / B, B, 0, stream>>>(dst, deg, E);
    dis_kernel<<<(n + B - 1) / B, B, 0, stream>>>(deg, dis, n);

    const int gemmGrid = (n + 63) / 64;
    const int vecGrid  = (n * 32 + B - 1) / B;   // 32 threads/row
    const int edgeGrid = (int)(((long long)E * 32 + B - 1) / B);

    // layer 1: bufA = x @ W1 ; bufB = b1 + selfloop + scatter
    gemm_128_128<false><<<gemmGrid, B, 0, stream>>>(x, W1, bufA, n);
    init_out_kernel<<<vecGrid, B, 0, stream>>>(bufA, dis, b1, bufB, n);
    edge_scatter_kernel<<<edgeGrid, B, 0, stream>>>(src, dst, dis, bufA, bufB, E);

    // layer 2: bufA = relu(bufB) @ W2 ; bufB = b2 + selfloop + scatter
    gemm_128_128<true><<<gemmGrid, B, 0, stream>>>(bufB, W2, bufA, n);
    init_out_kernel<<<vecGrid, B, 0, stream>>>(bufA, dis, b2, bufB, n);
    edge_scatter_kernel<<<edgeGrid, B, 0, stream>>>(src, dst, dis, bufA, bufB, E);

    // head: out = relu(bufB) @ Wh + bh
    head_kernel<<<(n + 15) / 16, B, 0, stream>>>(bufB, Wh, bh, out, n);
}

// Round 2
// 425.361 us; speedup vs baseline: 6.7826x; 6.7826x over previous
//
#include <hip/hip_runtime.h>

#define CH 128
#define NCLS 16
#define SCAN_IPB 1024   // items per block in scan pass 1

// ---------------------------------------------------------------- small utils
__global__ void zero_int_kernel(int* __restrict__ p, int n) {
    int i = blockIdx.x * blockDim.x + threadIdx.x;
    if (i < n) p[i] = 0;
}

__global__ void count_kernel(const int* __restrict__ dst,
                             int* __restrict__ cnt, int E) {
    int e = blockIdx.x * blockDim.x + threadIdx.x;
    if (e < E) atomicAdd(&cnt[dst[e]], 1);
}

__global__ void dis_kernel(const int* __restrict__ cnt,
                           float* __restrict__ dis, int n) {
    int i = blockIdx.x * blockDim.x + threadIdx.x;
    if (i < n) dis[i] = rsqrtf((float)cnt[i] + 1.0f);   // +1 = self-loop
}

// ---------------------------------------------------------------- scan (CSR)
__global__ __launch_bounds__(256) void scan1_kernel(
    const int* __restrict__ cnt, int* __restrict__ row_start,
    int* __restrict__ bsum, int n) {
    __shared__ int lds[256];
    int t = threadIdx.x, b = blockIdx.x;
    int base = b * SCAN_IPB + t * 4;
    int v[4];
    int s = 0;
#pragma unroll
    for (int k = 0; k < 4; k++) {
        v[k] = (base + k < n) ? cnt[base + k] : 0;
        s += v[k];
    }
    lds[t] = s;
    __syncthreads();
    for (int off = 1; off < 256; off <<= 1) {
        int x = (t >= off) ? lds[t - off] : 0;
        __syncthreads();
        lds[t] += x;
        __syncthreads();
    }
    int incl = lds[t];
    int run = incl - s;   // exclusive across threads
#pragma unroll
    for (int k = 0; k < 4; k++) {
        if (base + k < n) row_start[base + k] = run;
        run += v[k];
    }
    if (t == 255) bsum[b] = incl;
}

__global__ __launch_bounds__(256) void scan2_kernel(int* __restrict__ bsum, int nb) {
    __shared__ int lds[256];
    int t = threadIdx.x;
    int s = (t < nb) ? bsum[t] : 0;
    lds[t] = s;
    __syncthreads();
    for (int off = 1; off < 256; off <<= 1) {
        int x = (t >= off) ? lds[t - off] : 0;
        __syncthreads();
        lds[t] += x;
        __syncthreads();
    }
    if (t < nb) bsum[t] = lds[t] - s;   // exclusive
}

__global__ void scan3_kernel(int* __restrict__ row_start, int* __restrict__ cursor,
                             const int* __restrict__ bsum, int n, int E) {
    int i = blockIdx.x * blockDim.x + threadIdx.x;
    if (i < n) {
        int v = row_start[i] + bsum[i >> 10];   // >>10 == /SCAN_IPB
        row_start[i] = v;
        cursor[i] = v;
    }
    if (i == 0) row_start[n] = E;
}

__global__ void fill_kernel(const int* __restrict__ src, const int* __restrict__ dst,
                            int* __restrict__ cursor, int* __restrict__ esrc, int E) {
    int e = blockIdx.x * blockDim.x + threadIdx.x;
    if (e >= E) return;
    int p = atomicAdd(&cursor[dst[e]], 1);
    esrc[p] = src[e];
}

// ---------------------------------------------------------------- GEMM 128x128
template <bool RELU_IN>
__global__ __launch_bounds__(256) void gemm_128_128(
    const float* __restrict__ A, const float* __restrict__ W,
    float* __restrict__ C, int n_rows) {
    __shared__ float As[64][33];
    __shared__ float Ws[32][132];

    const int tid = threadIdx.x;
    const int bm0 = blockIdx.x * 64;
    const int tc = tid & 31;
    const int tr = tid >> 5;

    float acc[8][4];
#pragma unroll
    for (int i = 0; i < 8; i++)
#pragma unroll
        for (int j = 0; j < 4; j++) acc[i][j] = 0.0f;

    for (int k0 = 0; k0 < 128; k0 += 32) {
#pragma unroll
        for (int i = 0; i < 8; i++) {
            int l = tid + i * 256;
            int r = l >> 5, c = l & 31;
            int gr = bm0 + r;
            float v = (gr < n_rows) ? A[(size_t)gr * CH + k0 + c] : 0.0f;
            if (RELU_IN) v = fmaxf(v, 0.0f);
            As[r][c] = v;
        }
#pragma unroll
        for (int i = 0; i < 16; i++) {
            int l = tid + i * 256;
            int r = l >> 7, c = l & 127;
            Ws[r][c] = W[(k0 + r) * CH + c];
        }
        __syncthreads();
#pragma unroll
        for (int kk = 0; kk < 32; kk++) {
            float4 b = *(const float4*)&Ws[kk][tc * 4];
            float a[8];
#pragma unroll
            for (int i = 0; i < 8; i++) a[i] = As[tr * 8 + i][kk];
#pragma unroll
            for (int i = 0; i < 8; i++) {
                acc[i][0] = fmaf(a[i], b.x, acc[i][0]);
                acc[i][1] = fmaf(a[i], b.y, acc[i][1]);
                acc[i][2] = fmaf(a[i], b.z, acc[i][2]);
                acc[i][3] = fmaf(a[i], b.w, acc[i][3]);
            }
        }
        __syncthreads();
    }
#pragma unroll
    for (int i = 0; i < 8; i++) {
        int gr = bm0 + tr * 8 + i;
        if (gr < n_rows) {
            float4 v = make_float4(acc[i][0], acc[i][1], acc[i][2], acc[i][3]);
            *(float4*)&C[(size_t)gr * CH + tc * 4] = v;
        }
    }
}

// ---------------------------------------------------------------- CSR gather
// one 64-lane wave per dst node; lane handles 2 channels (float2)
// out[i,:] = bias + dis[i]^2*h[i,:] + sum_e dis[src]*dis[i]*h[src,:]
__global__ __launch_bounds__(256) void gather_kernel(
    const int* __restrict__ row_start, const int* __restrict__ esrc,
    const float* __restrict__ dis, const float* __restrict__ h,
    const float* __restrict__ bias, float* __restrict__ out, int n) {
    int wave = (blockIdx.x * 256 + threadIdx.x) >> 6;
    int lane = threadIdx.x & 63;
    if (wave >= n) return;
    const int i = wave;
    const float2* __restrict__ h2 = (const float2*)h;

    float di = dis[i];
    float2 hv = h2[(size_t)i * 64 + lane];
    float2 bv = ((const float2*)bias)[lane];
    float s2 = di * di;
    float accx = bv.x + s2 * hv.x;
    float accy = bv.y + s2 * hv.y;

    int beg = row_start[i], end = row_start[i + 1];
    for (int j0 = beg; j0 < end; j0 += 64) {
        int m = min(64, end - j0);
        int sidx = 0;
        float w = 0.0f;
        if (j0 + lane < end) {
            sidx = esrc[j0 + lane];
            w = dis[sidx] * di;
        }
        for (int j = 0; j < m; j++) {
            int sj = __shfl(sidx, j);
            float wj = __shfl(w, j);
            float2 hs = h2[(size_t)sj * 64 + lane];
            accx = fmaf(wj, hs.x, accx);
            accy = fmaf(wj, hs.y, accy);
        }
    }
    float2 o = make_float2(accx, accy);
    ((float2*)out)[(size_t)i * 64 + lane] = o;
}

// ---------------------------------------------------------------- head
__global__ __launch_bounds__(256) void head_kernel(
    const float* __restrict__ A, const float* __restrict__ Wh,
    const float* __restrict__ bh, float* __restrict__ out, int n) {
    __shared__ float Ws[CH * NCLS];
    __shared__ float As[16][129];
    const int tid = threadIdx.x;
    const int n0 = blockIdx.x * 16;
#pragma unroll
    for (int i = 0; i < 8; i++) {
        int l = tid + i * 256;
        Ws[l] = Wh[l];
    }
#pragma unroll
    for (int i = 0; i < 8; i++) {
        int l = tid + i * 256;
        int r = l >> 7, c = l & 127;
        int gr = n0 + r;
        As[r][c] = (gr < n) ? fmaxf(A[(size_t)gr * CH + c], 0.0f) : 0.0f;
    }
    __syncthreads();
    int r = tid >> 4, c = tid & 15;
    float acc = bh[c];
#pragma unroll
    for (int k = 0; k < CH; k++) acc = fmaf(As[r][k], Ws[k * NCLS + c], acc);
    int gr = n0 + r;
    if (gr < n) out[(size_t)gr * NCLS + c] = acc;
}

// ---------------------------------------------------------------- launch
extern "C" void kernel_launch(void* const* d_in, const int* in_sizes, int n_in,
                              void* d_out, int out_size, void* d_ws, size_t ws_size,
                              hipStream_t stream) {
    const float* x  = (const float*)d_in[0];
    const int*   ei = (const int*)d_in[1];
    const float* W1 = (const float*)d_in[2];
    const float* b1 = (const float*)d_in[3];
    const float* W2 = (const float*)d_in[4];
    const float* b2 = (const float*)d_in[5];
    const float* Wh = (const float*)d_in[6];
    const float* bh = (const float*)d_in[7];
    float* out = (float*)d_out;

    const int n = in_sizes[0] / CH;   // 50000
    const int E = in_sizes[1] / 2;    // 800000
    const int* src = ei;
    const int* dst = ei + E;

    // workspace layout (floats first for 16B alignment)
    float* dis  = (float*)d_ws;                 // n floats
    float* bufA = dis + n;                      // n*128
    float* bufB = bufA + (size_t)n * CH;        // n*128
    int* cnt       = (int*)(bufB + (size_t)n * CH);  // n
    int* row_start = cnt + n;                   // n+1
    int* cursor    = row_start + n + 1;         // n
    int* bsum      = cursor + n;                // up to 256
    int* esrc      = bsum + 256;                // E

    const int B = 256;
    const int nb_scan = (n + SCAN_IPB - 1) / SCAN_IPB;   // 49

    // ---- CSR build + normalization (once, reused by both layers)
    zero_int_kernel<<<(n + B - 1) / B, B, 0, stream>>>(cnt, n);
    count_kernel<<<(E + B - 1) / B, B, 0, stream>>>(dst, cnt, E);
    dis_kernel<<<(n + B - 1) / B, B, 0, stream>>>(cnt, dis, n);
    scan1_kernel<<<nb_scan, B, 0, stream>>>(cnt, row_start, bsum, n);
    scan2_kernel<<<1, B, 0, stream>>>(bsum, nb_scan);
    scan3_kernel<<<(n + B - 1) / B, B, 0, stream>>>(row_start, cursor, bsum, n, E);
    fill_kernel<<<(E + B - 1) / B, B, 0, stream>>>(src, dst, cursor, esrc, E);

    const int gemmGrid = (n + 63) / 64;
    const int gatherGrid = (n + 3) / 4;   // 4 waves (nodes) per 256-thread block

    // layer 1
    gemm_128_128<false><<<gemmGrid, B, 0, stream>>>(x, W1, bufA, n);
    gather_kernel<<<gatherGrid, B, 0, stream>>>(row_start, esrc, dis, bufA, b1, bufB, n);
    // layer 2
    gemm_128_128<true><<<gemmGrid, B, 0, stream>>>(bufB, W2, bufA, n);
    gather_kernel<<<gatherGrid, B, 0, stream>>>(row_start, esrc, dis, bufA, b2, bufB, n);
    // head
    head_kernel<<<(n + 15) / 16, B, 0, stream>>>(bufB, Wh, bh, out, n);
}

// Round 3
// 408.117 us; speedup vs baseline: 7.0692x; 1.0423x over previous
//
#include <hip/hip_runtime.h>

#define CH 128
#define NCLS 16
#define SCAN_IPB 1024   // items per block in scan pass 1

// ---------------------------------------------------------------- small utils
__global__ void zero_int_kernel(int* __restrict__ p, int n) {
    int i = blockIdx.x * blockDim.x + threadIdx.x;
    if (i < n) p[i] = 0;
}

__global__ void count_kernel(const int* __restrict__ dst,
                             int* __restrict__ cnt, int E) {
    int e = blockIdx.x * blockDim.x + threadIdx.x;
    if (e < E) atomicAdd(&cnt[dst[e]], 1);
}

__global__ void dis_kernel(const int* __restrict__ cnt,
                           float* __restrict__ dis, int n) {
    int i = blockIdx.x * blockDim.x + threadIdx.x;
    if (i < n) dis[i] = rsqrtf((float)cnt[i] + 1.0f);   // +1 = self-loop
}

// ---------------------------------------------------------------- scan (CSR)
__global__ __launch_bounds__(256) void scan1_kernel(
    const int* __restrict__ cnt, int* __restrict__ row_start,
    int* __restrict__ bsum, int n) {
    __shared__ int lds[256];
    int t = threadIdx.x, b = blockIdx.x;
    int base = b * SCAN_IPB + t * 4;
    int v[4];
    int s = 0;
#pragma unroll
    for (int k = 0; k < 4; k++) {
        v[k] = (base + k < n) ? cnt[base + k] : 0;
        s += v[k];
    }
    lds[t] = s;
    __syncthreads();
    for (int off = 1; off < 256; off <<= 1) {
        int x = (t >= off) ? lds[t - off] : 0;
        __syncthreads();
        lds[t] += x;
        __syncthreads();
    }
    int incl = lds[t];
    int run = incl - s;   // exclusive across threads
#pragma unroll
    for (int k = 0; k < 4; k++) {
        if (base + k < n) row_start[base + k] = run;
        run += v[k];
    }
    if (t == 255) bsum[b] = incl;
}

__global__ __launch_bounds__(256) void scan2_kernel(int* __restrict__ bsum, int nb) {
    __shared__ int lds[256];
    int t = threadIdx.x;
    int s = (t < nb) ? bsum[t] : 0;
    lds[t] = s;
    __syncthreads();
    for (int off = 1; off < 256; off <<= 1) {
        int x = (t >= off) ? lds[t - off] : 0;
        __syncthreads();
        lds[t] += x;
        __syncthreads();
    }
    if (t < nb) bsum[t] = lds[t] - s;   // exclusive
}

__global__ void scan3_kernel(int* __restrict__ row_start, int* __restrict__ cursor,
                             const int* __restrict__ bsum, int n, int E) {
    int i = blockIdx.x * blockDim.x + threadIdx.x;
    if (i < n) {
        int v = row_start[i] + bsum[i >> 10];   // >>10 == /SCAN_IPB
        row_start[i] = v;
        cursor[i] = v;
    }
    if (i == 0) row_start[n] = E;
}

__global__ void fill_kernel(const int* __restrict__ src, const int* __restrict__ dst,
                            int* __restrict__ cursor, int* __restrict__ esrc, int E) {
    int e = blockIdx.x * blockDim.x + threadIdx.x;
    if (e >= E) return;
    int p = atomicAdd(&cursor[dst[e]], 1);
    esrc[p] = src[e];
}

// ---------------------------------------------------------------- GEMM 128x128
template <bool RELU_IN>
__global__ __launch_bounds__(256) void gemm_128_128(
    const float* __restrict__ A, const float* __restrict__ W,
    float* __restrict__ C, int n_rows) {
    __shared__ float As[64][33];
    __shared__ float Ws[32][132];

    const int tid = threadIdx.x;
    const int bm0 = blockIdx.x * 64;
    const int tc = tid & 31;
    const int tr = tid >> 5;

    float acc[8][4];
#pragma unroll
    for (int i = 0; i < 8; i++)
#pragma unroll
        for (int j = 0; j < 4; j++) acc[i][j] = 0.0f;

    for (int k0 = 0; k0 < 128; k0 += 32) {
#pragma unroll
        for (int i = 0; i < 8; i++) {
            int l = tid + i * 256;
            int r = l >> 5, c = l & 31;
            int gr = bm0 + r;
            float v = (gr < n_rows) ? A[(size_t)gr * CH + k0 + c] : 0.0f;
            if (RELU_IN) v = fmaxf(v, 0.0f);
            As[r][c] = v;
        }
#pragma unroll
        for (int i = 0; i < 16; i++) {
            int l = tid + i * 256;
            int r = l >> 7, c = l & 127;
            Ws[r][c] = W[(k0 + r) * CH + c];
        }
        __syncthreads();
#pragma unroll
        for (int kk = 0; kk < 32; kk++) {
            float4 b = *(const float4*)&Ws[kk][tc * 4];
            float a[8];
#pragma unroll
            for (int i = 0; i < 8; i++) a[i] = As[tr * 8 + i][kk];
#pragma unroll
            for (int i = 0; i < 8; i++) {
                acc[i][0] = fmaf(a[i], b.x, acc[i][0]);
                acc[i][1] = fmaf(a[i], b.y, acc[i][1]);
                acc[i][2] = fmaf(a[i], b.z, acc[i][2]);
                acc[i][3] = fmaf(a[i], b.w, acc[i][3]);
            }
        }
        __syncthreads();
    }
#pragma unroll
    for (int i = 0; i < 8; i++) {
        int gr = bm0 + tr * 8 + i;
        if (gr < n_rows) {
            float4 v = make_float4(acc[i][0], acc[i][1], acc[i][2], acc[i][3]);
            *(float4*)&C[(size_t)gr * CH + tc * 4] = v;
        }
    }
}

// ---------------------------------------------------------------- CSR gather
// one 64-lane wave per dst node; lane handles 2 channels (float2).
// 8-way unrolled edge loop => 8 independent h-row loads in flight per wave.
// Out-of-range lanes carry (sidx=0, w=0) so the unrolled body needs no
// remainder loop: zero-weight steps re-read row 0 (L1-hot), contribute 0.
__global__ __launch_bounds__(256) void gather_kernel(
    const int* __restrict__ row_start, const int* __restrict__ esrc,
    const float* __restrict__ dis, const float* __restrict__ h,
    const float* __restrict__ bias, float* __restrict__ out, int n) {
    int wave = (blockIdx.x * 256 + threadIdx.x) >> 6;
    int lane = threadIdx.x & 63;
    if (wave >= n) return;
    const int i = wave;
    const float2* __restrict__ h2 = (const float2*)h;

    float di = dis[i];
    float2 hv = h2[(size_t)i * 64 + lane];
    float2 bv = ((const float2*)bias)[lane];
    float s2 = di * di;
    float accx = bv.x + s2 * hv.x;
    float accy = bv.y + s2 * hv.y;

    int beg = row_start[i], end = row_start[i + 1];
    for (int j0 = beg; j0 < end; j0 += 64) {
        int m = min(64, end - j0);
        int sidx = 0;
        float w = 0.0f;
        if (j0 + lane < end) {
            sidx = esrc[j0 + lane];
            w = dis[sidx] * di;
        }
        int m8 = (m + 7) & ~7;   // round up; extra steps have w=0
        for (int j = 0; j < m8; j += 8) {
            int s0 = __shfl(sidx, j + 0), s1 = __shfl(sidx, j + 1);
            int s2i = __shfl(sidx, j + 2), s3 = __shfl(sidx, j + 3);
            int s4 = __shfl(sidx, j + 4), s5 = __shfl(sidx, j + 5);
            int s6 = __shfl(sidx, j + 6), s7 = __shfl(sidx, j + 7);
            float w0 = __shfl(w, j + 0), w1 = __shfl(w, j + 1);
            float w2 = __shfl(w, j + 2), w3 = __shfl(w, j + 3);
            float w4 = __shfl(w, j + 4), w5 = __shfl(w, j + 5);
            float w6 = __shfl(w, j + 6), w7 = __shfl(w, j + 7);
            float2 r0 = h2[(size_t)s0 * 64 + lane];
            float2 r1 = h2[(size_t)s1 * 64 + lane];
            float2 r2 = h2[(size_t)s2i * 64 + lane];
            float2 r3 = h2[(size_t)s3 * 64 + lane];
            float2 r4 = h2[(size_t)s4 * 64 + lane];
            float2 r5 = h2[(size_t)s5 * 64 + lane];
            float2 r6 = h2[(size_t)s6 * 64 + lane];
            float2 r7 = h2[(size_t)s7 * 64 + lane];
            accx = fmaf(w0, r0.x, accx); accy = fmaf(w0, r0.y, accy);
            accx = fmaf(w1, r1.x, accx); accy = fmaf(w1, r1.y, accy);
            accx = fmaf(w2, r2.x, accx); accy = fmaf(w2, r2.y, accy);
            accx = fmaf(w3, r3.x, accx); accy = fmaf(w3, r3.y, accy);
            accx = fmaf(w4, r4.x, accx); accy = fmaf(w4, r4.y, accy);
            accx = fmaf(w5, r5.x, accx); accy = fmaf(w5, r5.y, accy);
            accx = fmaf(w6, r6.x, accx); accy = fmaf(w6, r6.y, accy);
            accx = fmaf(w7, r7.x, accx); accy = fmaf(w7, r7.y, accy);
        }
    }
    ((float2*)out)[(size_t)i * 64 + lane] = make_float2(accx, accy);
}

// ---------------------------------------------------------------- head
__global__ __launch_bounds__(256) void head_kernel(
    const float* __restrict__ A, const float* __restrict__ Wh,
    const float* __restrict__ bh, float* __restrict__ out, int n) {
    __shared__ float Ws[CH * NCLS];
    __shared__ float As[16][129];
    const int tid = threadIdx.x;
    const int n0 = blockIdx.x * 16;
#pragma unroll
    for (int i = 0; i < 8; i++) {
        int l = tid + i * 256;
        Ws[l] = Wh[l];
    }
#pragma unroll
    for (int i = 0; i < 8; i++) {
        int l = tid + i * 256;
        int r = l >> 7, c = l & 127;
        int gr = n0 + r;
        As[r][c] = (gr < n) ? fmaxf(A[(size_t)gr * CH + c], 0.0f) : 0.0f;
    }
    __syncthreads();
    int r = tid >> 4, c = tid & 15;
    float acc = bh[c];
#pragma unroll
    for (int k = 0; k < CH; k++) acc = fmaf(As[r][k], Ws[k * NCLS + c], acc);
    int gr = n0 + r;
    if (gr < n) out[(size_t)gr * NCLS + c] = acc;
}

// ---------------------------------------------------------------- launch
extern "C" void kernel_launch(void* const* d_in, const int* in_sizes, int n_in,
                              void* d_out, int out_size, void* d_ws, size_t ws_size,
                              hipStream_t stream) {
    const float* x  = (const float*)d_in[0];
    const int*   ei = (const int*)d_in[1];
    const float* W1 = (const float*)d_in[2];
    const float* b1 = (const float*)d_in[3];
    const float* W2 = (const float*)d_in[4];
    const float* b2 = (const float*)d_in[5];
    const float* Wh = (const float*)d_in[6];
    const float* bh = (const float*)d_in[7];
    float* out = (float*)d_out;

    const int n = in_sizes[0] / CH;   // 50000
    const int E = in_sizes[1] / 2;    // 800000
    const int* src = ei;
    const int* dst = ei + E;

    // workspace layout (floats first for 16B alignment)
    float* dis  = (float*)d_ws;                 // n floats
    float* bufA = dis + n;                      // n*128
    float* bufB = bufA + (size_t)n * CH;        // n*128
    int* cnt       = (int*)(bufB + (size_t)n * CH);  // n
    int* row_start = cnt + n;                   // n+1
    int* cursor    = row_start + n + 1;         // n
    int* bsum      = cursor + n;                // up to 256
    int* esrc      = bsum + 256;                // E

    const int B = 256;
    const int nb_scan = (n + SCAN_IPB - 1) / SCAN_IPB;   // 49

    // ---- CSR build + normalization (once, reused by both layers)
    zero_int_kernel<<<(n + B - 1) / B, B, 0, stream>>>(cnt, n);
    count_kernel<<<(E + B - 1) / B, B, 0, stream>>>(dst, cnt, E);
    dis_kernel<<<(n + B - 1) / B, B, 0, stream>>>(cnt, dis, n);
    scan1_kernel<<<nb_scan, B, 0, stream>>>(cnt, row_start, bsum, n);
    scan2_kernel<<<1, B, 0, stream>>>(bsum, nb_scan);
    scan3_kernel<<<(n + B - 1) / B, B, 0, stream>>>(row_start, cursor, bsum, n, E);
    fill_kernel<<<(E + B - 1) / B, B, 0, stream>>>(src, dst, cursor, esrc, E);

    const int gemmGrid = (n + 63) / 64;
    const int gatherGrid = (n + 3) / 4;   // 4 waves (nodes) per 256-thread block

    // layer 1
    gemm_128_128<false><<<gemmGrid, B, 0, stream>>>(x, W1, bufA, n);
    gather_kernel<<<gatherGrid, B, 0, stream>>>(row_start, esrc, dis, bufA, b1, bufB, n);
    // layer 2
    gemm_128_128<true><<<gemmGrid, B, 0, stream>>>(bufB, W2, bufA, n);
    gather_kernel<<<gatherGrid, B, 0, stream>>>(row_start, esrc, dis, bufA, b2, bufB, n);
    // head
    head_kernel<<<(n + 15) / 16, B, 0, stream>>>(bufB, Wh, bh, out, n);
}